// Round 1
// baseline (664.908 us; speedup 1.0000x reference)
//
#include <hip/hip_runtime.h>

#define EPS 1e-5f
#define SLOPE 0.01f

static __device__ __forceinline__ float atomicAddF(float* p, float v){
  return __hip_atomic_fetch_add(p, v, __ATOMIC_RELAXED, __HIP_MEMORY_SCOPE_AGENT);
}

// ---- preprocessing -------------------------------------------------------

__global__ void k_deg_cnt(const int* __restrict__ dst, const float* __restrict__ w,
                          float* __restrict__ deg, int* __restrict__ cnt, int E){
  int e = blockIdx.x*blockDim.x + threadIdx.x;
  if (e >= E) return;
  int d = dst[e];
  atomicAddF(&deg[d], w[e]);
  atomicAdd(&cnt[d], 1);
}

__global__ void k_dinv(const float* __restrict__ deg, float* __restrict__ dinv,
                       float* __restrict__ selfn, int n){
  int i = blockIdx.x*blockDim.x + threadIdx.x;
  if (i >= n) return;
  float dg = deg[i] + 1.0f;          // + self-loop weight; always > 0
  dinv[i]  = rsqrtf(dg);
  selfn[i] = 1.0f / dg;              // dinv*1*dinv for the self loop
}

// single-block exclusive scan (wave-shfl based), writes rowptr[0..n] and next_
__global__ void k_scan(const int* __restrict__ cnt, int* __restrict__ rowptr,
                       int* __restrict__ next_, int n){
  __shared__ int wtot[16];
  __shared__ int woff[16];
  __shared__ int carry;
  int tid  = threadIdx.x;
  int lane = tid & 63;
  int wid  = tid >> 6;
  if (tid == 0) carry = 0;
  __syncthreads();
  for (int base = 0; base < n; base += 1024){
    int idx = base + tid;
    int v = (idx < n) ? cnt[idx] : 0;
    int incl = v;
    #pragma unroll
    for (int off = 1; off < 64; off <<= 1){
      int u = __shfl_up(incl, off, 64);
      if (lane >= off) incl += u;
    }
    if (lane == 63) wtot[wid] = incl;
    __syncthreads();
    if (tid < 64){
      int cr = carry;
      int x = (lane < 16) ? wtot[lane] : 0;
      int inc2 = x;
      #pragma unroll
      for (int off = 1; off < 16; off <<= 1){
        int u = __shfl_up(inc2, off, 64);
        if (lane >= off) inc2 += u;
      }
      if (lane < 16) woff[lane] = cr + inc2 - x;
      if (lane == 15) carry = cr + inc2;   // same-wave: reads of carry precede this
    }
    __syncthreads();
    int excl = woff[wid] + incl - v;
    if (idx < n){ rowptr[idx] = excl; next_[idx] = excl; }
    __syncthreads();
  }
  if (tid == 0) rowptr[n] = carry;
}

__global__ void k_fill(const int* __restrict__ src, const int* __restrict__ dst,
                       const float* __restrict__ w, const float* __restrict__ dinv,
                       int* __restrict__ next_, int* __restrict__ csr_src,
                       float* __restrict__ csr_norm, int E){
  int e = blockIdx.x*blockDim.x + threadIdx.x;
  if (e >= E) return;
  int s = src[e], d = dst[e];
  float nr = dinv[s] * w[e] * dinv[d];
  int pos = atomicAdd(&next_[d], 1);
  csr_src[pos]  = s;
  csr_norm[pos] = nr;
}

__global__ void k_find_starts(const int* __restrict__ batch, int* __restrict__ start,
                              int n, int g){
  int i = blockIdx.x*blockDim.x + threadIdx.x;
  if (i >= n) return;
  int b  = batch[i];
  int bp = (i == 0) ? -1 : batch[i-1];
  for (int q = bp + 1; q <= b; ++q) start[q] = i;
  if (i == n - 1){
    for (int q = b + 1; q <= g; ++q) start[q] = n;
  }
}

// ---- dense GEMM: Y[n,128] = X[n,128] @ W[128,128] (f32, VALU) ------------

__global__ __launch_bounds__(256) void k_gemm(const float* __restrict__ X,
                                              const float* __restrict__ W,
                                              float* __restrict__ Y, int nrows){
  __shared__ float xs[64][128];
  int t  = threadIdx.x;
  int c  = t & 127;       // output column
  int rg = t >> 7;        // row group 0/1 (32 rows each)
  int row0 = blockIdx.x * 64;

  const float4* x4 = (const float4*)X;
  #pragma unroll
  for (int i = 0; i < 8; ++i){
    int lin = i*256 + t;          // 0..2047 float4s
    int r  = lin >> 5;            // 0..63
    int cc = lin & 31;            // 0..31 float4 within row
    int gr = row0 + r; if (gr >= nrows) gr = nrows - 1;
    ((float4*)xs)[r*32 + cc] = x4[(size_t)gr*32 + cc];
  }
  __syncthreads();

  float acc[32];
  #pragma unroll
  for (int r = 0; r < 32; ++r) acc[r] = 0.f;

  const float* xb = &xs[rg*32][0];
  for (int k = 0; k < 128; k += 4){
    float w0 = W[(k+0)*128 + c];
    float w1 = W[(k+1)*128 + c];
    float w2 = W[(k+2)*128 + c];
    float w3 = W[(k+3)*128 + c];
    #pragma unroll
    for (int r = 0; r < 32; ++r){
      float4 xv = *(const float4*)&xb[r*128 + k];   // broadcast read
      acc[r] += xv.x*w0 + xv.y*w1 + xv.z*w2 + xv.w*w3;
    }
  }

  #pragma unroll
  for (int r = 0; r < 32; ++r){
    int gr = row0 + rg*32 + r;
    if (gr < nrows) Y[(size_t)gr*128 + c] = acc[r];
  }
}

// ---- CSR gather + bias (+BN+leaky) --------------------------------------
// one wave per node; lane handles channels 2l, 2l+1

template<bool BN>
__global__ void k_gather(const float* __restrict__ y, const int* __restrict__ rowptr,
                         const int* __restrict__ csr_src, const float* __restrict__ csr_norm,
                         const float* __restrict__ selfn,
                         const float* __restrict__ bias,
                         const float* __restrict__ gam, const float* __restrict__ bet,
                         const float* __restrict__ mean, const float* __restrict__ var,
                         float* __restrict__ out, int n){
  int wid  = (blockIdx.x * blockDim.x + threadIdx.x) >> 6;   // node
  int lane = threadIdx.x & 63;
  if (wid >= n) return;
  const float2* y2 = (const float2*)y;
  float2 acc = y2[(size_t)wid*64 + lane];
  float sn = selfn[wid];
  acc.x *= sn; acc.y *= sn;
  int e0 = rowptr[wid], e1 = rowptr[wid+1];
  for (int e = e0; e < e1; ++e){
    int   s  = csr_src[e];
    float nr = csr_norm[e];
    float2 yv = y2[(size_t)s*64 + lane];
    acc.x += yv.x * nr;
    acc.y += yv.y * nr;
  }
  int c = lane*2;
  float o0 = acc.x + bias[c];
  float o1 = acc.y + bias[c+1];
  if (BN){
    float a0 = gam[c]   * rsqrtf(var[c]   + EPS);
    float a1 = gam[c+1] * rsqrtf(var[c+1] + EPS);
    o0 = (o0 - mean[c])   * a0 + bet[c];
    o1 = (o1 - mean[c+1]) * a1 + bet[c+1];
    o0 = o0 > 0.f ? o0 : SLOPE*o0;
    o1 = o1 > 0.f ? o1 : SLOPE*o1;
  }
  ((float2*)out)[(size_t)wid*64 + lane] = make_float2(o0, o1);
}

// ---- mean pool over sorted batch ----------------------------------------

__global__ void k_pool(const float* __restrict__ h, const int* __restrict__ start,
                       float* __restrict__ out){
  __shared__ float red[512];
  int g = blockIdx.x;
  int a = start[g], b = start[g+1];
  int rg = threadIdx.x >> 7;     // 0..3
  int c  = threadIdx.x & 127;
  float s = 0.f;
  for (int i = a + rg; i < b; i += 4) s += h[(size_t)i*128 + c];
  red[threadIdx.x] = s;
  __syncthreads();
  if (rg == 0){
    float tot = red[c] + red[c+128] + red[c+256] + red[c+384];
    int cn = b - a;
    out[g*128 + c] = tot / (float)(cn > 0 ? cn : 1);
  }
}

// ---- launch --------------------------------------------------------------

extern "C" void kernel_launch(void* const* d_in, const int* in_sizes, int n_in,
                              void* d_out, int out_size, void* d_ws, size_t ws_size,
                              hipStream_t stream) {
  const int N = in_sizes[0] / 128;
  const int E = in_sizes[1];
  const int G = out_size / 128;

  const float* x   = (const float*)d_in[0];
  const float* ew  = (const float*)d_in[1];
  const float* W0  = (const float*)d_in[2];
  const float* b0  = (const float*)d_in[3];
  const float* W1  = (const float*)d_in[4];
  const float* b1  = (const float*)d_in[5];
  const float* W2  = (const float*)d_in[6];
  const float* b2  = (const float*)d_in[7];
  const float* g0  = (const float*)d_in[8];
  const float* be0 = (const float*)d_in[9];
  const float* m0  = (const float*)d_in[10];
  const float* v0  = (const float*)d_in[11];
  const float* g1  = (const float*)d_in[12];
  const float* be1 = (const float*)d_in[13];
  const float* m1  = (const float*)d_in[14];
  const float* v1  = (const float*)d_in[15];
  const int*   ei  = (const int*)d_in[16];
  const int*   bat = (const int*)d_in[17];
  float* out = (float*)d_out;

  char* p = (char*)d_ws;
  auto alloc = [&](size_t bytes)->char*{
    char* q = p; p += (bytes + 255) & ~(size_t)255; return q;
  };
  float* deg    = (float*)alloc((size_t)N*4);
  float* dinv   = (float*)alloc((size_t)N*4);
  float* selfn  = (float*)alloc((size_t)N*4);
  int*   cnt    = (int*)  alloc((size_t)N*4);
  int*   rowptr = (int*)  alloc((size_t)(N+1)*4);
  int*   next_  = (int*)  alloc((size_t)N*4);
  int*   start  = (int*)  alloc((size_t)(G+1)*4);
  int*   csr_s  = (int*)  alloc((size_t)E*4);
  float* csr_n  = (float*)alloc((size_t)E*4);
  float* Y      = (float*)alloc((size_t)N*128*4);
  float* H      = (float*)alloc((size_t)N*128*4);

  hipMemsetAsync(deg, 0, (size_t)N*4, stream);
  hipMemsetAsync(cnt, 0, (size_t)N*4, stream);

  const int* src = ei;
  const int* dst = ei + E;

  k_deg_cnt<<<(E+255)/256, 256, 0, stream>>>(dst, ew, deg, cnt, E);
  k_dinv   <<<(N+255)/256, 256, 0, stream>>>(deg, dinv, selfn, N);
  k_scan   <<<1, 1024, 0, stream>>>(cnt, rowptr, next_, N);
  k_fill   <<<(E+255)/256, 256, 0, stream>>>(src, dst, ew, dinv, next_, csr_s, csr_n, E);
  k_find_starts<<<(N+255)/256, 256, 0, stream>>>(bat, start, N, G);

  k_gemm<<<(N+63)/64, 256, 0, stream>>>(x, W0, Y, N);
  k_gather<true><<<(N+3)/4, 256, 0, stream>>>(Y, rowptr, csr_s, csr_n, selfn,
                                              b0, g0, be0, m0, v0, H, N);
  k_gemm<<<(N+63)/64, 256, 0, stream>>>(H, W1, Y, N);
  k_gather<true><<<(N+3)/4, 256, 0, stream>>>(Y, rowptr, csr_s, csr_n, selfn,
                                              b1, g1, be1, m1, v1, H, N);
  k_gemm<<<(N+63)/64, 256, 0, stream>>>(H, W2, Y, N);
  k_gather<false><<<(N+3)/4, 256, 0, stream>>>(Y, rowptr, csr_s, csr_n, selfn,
                                               b2, nullptr, nullptr, nullptr, nullptr, H, N);
  k_pool<<<G, 512, 0, stream>>>(H, start, out);
}

// Round 2
// 393.094 us; speedup vs baseline: 1.6915x; 1.6915x over previous
//
#include <hip/hip_runtime.h>

#define EPS 1e-5f
#define SLOPE 0.01f

typedef short short8 __attribute__((ext_vector_type(8)));
typedef float f32x4 __attribute__((ext_vector_type(4)));

static __device__ __forceinline__ float atomicAddF(float* p, float v){
  return __hip_atomic_fetch_add(p, v, __ATOMIC_RELAXED, __HIP_MEMORY_SCOPE_AGENT);
}

static __device__ __forceinline__ unsigned short f32_to_bf16(float x){
  unsigned int u = __float_as_uint(x);
  unsigned int r = u + 0x7FFFu + ((u >> 16) & 1u);
  return (unsigned short)(r >> 16);
}
static __device__ __forceinline__ float bf16lo_to_f32(unsigned int v){
  return __uint_as_float(v << 16);
}
static __device__ __forceinline__ float bf16hi_to_f32(unsigned int v){
  return __uint_as_float(v & 0xFFFF0000u);
}

// ---- preprocessing -------------------------------------------------------

__global__ void k_deg_cnt(const int* __restrict__ dst, const float* __restrict__ w,
                          float* __restrict__ deg, int* __restrict__ cnt, int E){
  int e = blockIdx.x*blockDim.x + threadIdx.x;
  if (e >= E) return;
  int d = dst[e];
  atomicAddF(&deg[d], w[e]);
  atomicAdd(&cnt[d], 1);
}

__global__ void k_dinv(const float* __restrict__ deg, float* __restrict__ dinv,
                       float* __restrict__ selfn, int n){
  int i = blockIdx.x*blockDim.x + threadIdx.x;
  if (i >= n) return;
  float dg = deg[i] + 1.0f;          // + self-loop weight; always > 0
  dinv[i]  = rsqrtf(dg);
  selfn[i] = 1.0f / dg;              // dinv*1*dinv for the self loop
}

// 256-thread block exclusive scan helper
static __device__ __forceinline__ int blk_excl_scan(int v){
  __shared__ int wt[4];
  int lane = threadIdx.x & 63, wv = threadIdx.x >> 6;
  int incl = v;
  #pragma unroll
  for (int o = 1; o < 64; o <<= 1){
    int u = __shfl_up(incl, o, 64);
    if (lane >= o) incl += u;
  }
  if (lane == 63) wt[wv] = incl;
  __syncthreads();
  int off = 0;
  #pragma unroll
  for (int i = 0; i < 4; ++i) if (i < wv) off += wt[i];
  return off + incl - v;
}

__global__ void k_scan_a(const int* __restrict__ cnt, int* __restrict__ bsum, int n){
  int idx = blockIdx.x*256 + threadIdx.x;
  int v = (idx < n) ? cnt[idx] : 0;
  int ex = blk_excl_scan(v);
  if (threadIdx.x == 255) bsum[blockIdx.x] = ex + v;
}

__global__ void k_scan_b(const int* __restrict__ bsum, int* __restrict__ boff, int nb){
  int v = (threadIdx.x < nb) ? bsum[threadIdx.x] : 0;
  int ex = blk_excl_scan(v);
  if (threadIdx.x < nb) boff[threadIdx.x] = ex;
}

__global__ void k_scan_c(const int* __restrict__ cnt, const int* __restrict__ boff,
                         int* __restrict__ rowptr, int* __restrict__ next_, int n, int Etot){
  int idx = blockIdx.x*256 + threadIdx.x;
  int v = (idx < n) ? cnt[idx] : 0;
  int ex = blk_excl_scan(v) + boff[blockIdx.x];
  if (idx < n){ rowptr[idx] = ex; next_[idx] = ex; }
  if (idx == 0) rowptr[n] = Etot;
}

__global__ void k_fill(const int* __restrict__ src, const int* __restrict__ dst,
                       const float* __restrict__ w, const float* __restrict__ dinv,
                       int* __restrict__ next_, int* __restrict__ csr_src,
                       float* __restrict__ csr_norm, int E){
  int e = blockIdx.x*blockDim.x + threadIdx.x;
  if (e >= E) return;
  int s = src[e], d = dst[e];
  float nr = dinv[s] * w[e] * dinv[d];
  int pos = atomicAdd(&next_[d], 1);
  csr_src[pos]  = s;
  csr_norm[pos] = nr;
}

__global__ void k_find_starts(const int* __restrict__ batch, int* __restrict__ start,
                              int n, int g){
  int i = blockIdx.x*blockDim.x + threadIdx.x;
  if (i >= n) return;
  int b  = batch[i];
  int bp = (i == 0) ? -1 : batch[i-1];
  for (int q = bp + 1; q <= b; ++q) start[q] = i;
  if (i == n - 1){
    for (int q = b + 1; q <= g; ++q) start[q] = n;
  }
}

// ---- weight pre-pack into MFMA B-fragment order (hi/lo bf16 split) -------
// B frag for tile t (n0=t*16), kstep s (k0=s*32), lane l, elem j:
//   value W[k][n], k = s*32 + (l>>4)*8 + j, n = t*16 + (l&15)
// stored at [( t*4 + s )*64 + l]*8 + j

__global__ void k_packW(const float* __restrict__ W, short* __restrict__ Bh,
                        short* __restrict__ Bl){
  int idx = blockIdx.x*256 + threadIdx.x;    // 0..16383
  int j = idx & 7;
  int l = (idx >> 3) & 63;
  int s = (idx >> 9) & 3;
  int t = idx >> 11;
  int k = s*32 + ((l >> 4) << 3) + j;
  int n = t*16 + (l & 15);
  float v = W[k*128 + n];
  unsigned short hb = f32_to_bf16(v);
  float hf = bf16lo_to_f32(hb);
  unsigned short lb = f32_to_bf16(v - hf);
  Bh[idx] = (short)hb;
  Bl[idx] = (short)lb;
}

// ---- dense GEMM: Y[n,128](bf16) = X[n,128](f32) @ W (split-bf16 MFMA) ----

__global__ __launch_bounds__(256) void k_gemm_mfma(const float* __restrict__ X,
                                                   const short* __restrict__ Bh,
                                                   const short* __restrict__ Bl,
                                                   unsigned short* __restrict__ Y,
                                                   int nrows){
  int w    = threadIdx.x >> 6;
  int lane = threadIdx.x & 63;
  int m    = lane & 15;
  int kg   = lane >> 4;
  int row0 = blockIdx.x*64 + w*16;

  f32x4 acc[8];
  #pragma unroll
  for (int t = 0; t < 8; ++t) acc[t] = (f32x4){0.f, 0.f, 0.f, 0.f};

  int arow = row0 + m;
  if (arow >= nrows) arow = nrows - 1;
  const float* ap0 = X + (size_t)arow*128 + (kg << 3);

  const short8* bh0 = (const short8*)Bh + lane;
  const short8* bl0 = (const short8*)Bl + lane;

  #pragma unroll
  for (int s = 0; s < 4; ++s){
    const float* ap = ap0 + s*32;
    float4 a0 = *(const float4*)ap;
    float4 a1 = *(const float4*)(ap + 4);
    float av[8] = {a0.x, a0.y, a0.z, a0.w, a1.x, a1.y, a1.z, a1.w};
    short8 ah, al;
    #pragma unroll
    for (int j = 0; j < 8; ++j){
      unsigned short hb = f32_to_bf16(av[j]);
      float hf = bf16lo_to_f32(hb);
      ah[j] = (short)hb;
      al[j] = (short)f32_to_bf16(av[j] - hf);
    }
    #pragma unroll
    for (int t = 0; t < 8; ++t){
      short8 bh = bh0[t*256 + s*64];
      short8 bl = bl0[t*256 + s*64];
      acc[t] = __builtin_amdgcn_mfma_f32_16x16x32_bf16(ah, bh, acc[t], 0, 0, 0);
      acc[t] = __builtin_amdgcn_mfma_f32_16x16x32_bf16(al, bh, acc[t], 0, 0, 0);
      acc[t] = __builtin_amdgcn_mfma_f32_16x16x32_bf16(ah, bl, acc[t], 0, 0, 0);
    }
  }

  // C/D: col = lane&15, row = (lane>>4)*4 + reg
  #pragma unroll
  for (int t = 0; t < 8; ++t){
    #pragma unroll
    for (int r = 0; r < 4; ++r){
      int grow = row0 + (kg << 2) + r;
      if (grow < nrows) Y[(size_t)grow*128 + t*16 + m] = f32_to_bf16(acc[t][r]);
    }
  }
}

// ---- CSR gather + bias (+BN+leaky); Y is bf16, out f32 -------------------
// one wave per node; lane handles channels 2l, 2l+1 (one u32 of 2 bf16)

template<bool BN>
__global__ void k_gather(const unsigned int* __restrict__ y, const int* __restrict__ rowptr,
                         const int* __restrict__ csr_src, const float* __restrict__ csr_norm,
                         const float* __restrict__ selfn,
                         const float* __restrict__ bias,
                         const float* __restrict__ gam, const float* __restrict__ bet,
                         const float* __restrict__ mean, const float* __restrict__ var,
                         float* __restrict__ out, int n){
  int wid  = (blockIdx.x * blockDim.x + threadIdx.x) >> 6;   // node
  int lane = threadIdx.x & 63;
  if (wid >= n) return;
  unsigned int v0 = y[(size_t)wid*64 + lane];
  float sn = selfn[wid];
  float ax = bf16lo_to_f32(v0) * sn;
  float ay = bf16hi_to_f32(v0) * sn;
  int e0 = rowptr[wid], e1 = rowptr[wid+1];
  int e = e0;
  for (; e + 2 <= e1; e += 2){
    int   s0 = csr_src[e],     s1 = csr_src[e+1];
    float n0 = csr_norm[e],    n1 = csr_norm[e+1];
    unsigned int yv0 = y[(size_t)s0*64 + lane];
    unsigned int yv1 = y[(size_t)s1*64 + lane];
    ax += bf16lo_to_f32(yv0) * n0;
    ay += bf16hi_to_f32(yv0) * n0;
    ax += bf16lo_to_f32(yv1) * n1;
    ay += bf16hi_to_f32(yv1) * n1;
  }
  if (e < e1){
    int   s0 = csr_src[e];
    float n0 = csr_norm[e];
    unsigned int yv0 = y[(size_t)s0*64 + lane];
    ax += bf16lo_to_f32(yv0) * n0;
    ay += bf16hi_to_f32(yv0) * n0;
  }
  int c = lane*2;
  float o0 = ax + bias[c];
  float o1 = ay + bias[c+1];
  if (BN){
    float a0 = gam[c]   * rsqrtf(var[c]   + EPS);
    float a1 = gam[c+1] * rsqrtf(var[c+1] + EPS);
    o0 = (o0 - mean[c])   * a0 + bet[c];
    o1 = (o1 - mean[c+1]) * a1 + bet[c+1];
    o0 = o0 > 0.f ? o0 : SLOPE*o0;
    o1 = o1 > 0.f ? o1 : SLOPE*o1;
  }
  ((float2*)out)[(size_t)wid*64 + lane] = make_float2(o0, o1);
}

// ---- mean pool over sorted batch ----------------------------------------

__global__ void k_pool(const float* __restrict__ h, const int* __restrict__ start,
                       float* __restrict__ out){
  __shared__ float red[1024];
  int g = blockIdx.x;
  int a = start[g], b = start[g+1];
  int rg = threadIdx.x >> 7;     // 0..7
  int c  = threadIdx.x & 127;
  float s = 0.f;
  for (int i = a + rg; i < b; i += 8) s += h[(size_t)i*128 + c];
  red[threadIdx.x] = s;
  __syncthreads();
  if (rg == 0){
    float tot = 0.f;
    #pragma unroll
    for (int q = 0; q < 8; ++q) tot += red[c + q*128];
    int cn = b - a;
    out[g*128 + c] = tot / (float)(cn > 0 ? cn : 1);
  }
}

// ---- launch --------------------------------------------------------------

extern "C" void kernel_launch(void* const* d_in, const int* in_sizes, int n_in,
                              void* d_out, int out_size, void* d_ws, size_t ws_size,
                              hipStream_t stream) {
  const int N = in_sizes[0] / 128;
  const int E = in_sizes[1];
  const int G = out_size / 128;
  const int NB = (N + 255) / 256;        // scan blocks

  const float* x   = (const float*)d_in[0];
  const float* ew  = (const float*)d_in[1];
  const float* W0  = (const float*)d_in[2];
  const float* b0  = (const float*)d_in[3];
  const float* W1  = (const float*)d_in[4];
  const float* b1  = (const float*)d_in[5];
  const float* W2  = (const float*)d_in[6];
  const float* b2  = (const float*)d_in[7];
  const float* g0  = (const float*)d_in[8];
  const float* be0 = (const float*)d_in[9];
  const float* m0  = (const float*)d_in[10];
  const float* v0  = (const float*)d_in[11];
  const float* g1  = (const float*)d_in[12];
  const float* be1 = (const float*)d_in[13];
  const float* m1  = (const float*)d_in[14];
  const float* v1  = (const float*)d_in[15];
  const int*   ei  = (const int*)d_in[16];
  const int*   bat = (const int*)d_in[17];
  float* out = (float*)d_out;

  char* p = (char*)d_ws;
  auto alloc = [&](size_t bytes)->char*{
    char* q = p; p += (bytes + 255) & ~(size_t)255; return q;
  };
  float* deg    = (float*)alloc((size_t)N*4);
  float* dinv   = (float*)alloc((size_t)N*4);
  float* selfn  = (float*)alloc((size_t)N*4);
  int*   cnt    = (int*)  alloc((size_t)N*4);
  int*   rowptr = (int*)  alloc((size_t)(N+1)*4);
  int*   next_  = (int*)  alloc((size_t)N*4);
  int*   start  = (int*)  alloc((size_t)(G+1)*4);
  int*   bsum   = (int*)  alloc((size_t)NB*4);
  int*   boff   = (int*)  alloc((size_t)NB*4);
  int*   csr_s  = (int*)  alloc((size_t)E*4);
  float* csr_n  = (float*)alloc((size_t)E*4);
  unsigned short* Y = (unsigned short*)alloc((size_t)N*128*2);
  float* H      = (float*)alloc((size_t)N*128*4);
  short* Bh0 = (short*)alloc(16384*2); short* Bl0 = (short*)alloc(16384*2);
  short* Bh1 = (short*)alloc(16384*2); short* Bl1 = (short*)alloc(16384*2);
  short* Bh2 = (short*)alloc(16384*2); short* Bl2 = (short*)alloc(16384*2);

  hipMemsetAsync(deg, 0, (size_t)N*4, stream);
  hipMemsetAsync(cnt, 0, (size_t)N*4, stream);

  const int* src = ei;
  const int* dst = ei + E;

  k_deg_cnt<<<(E+255)/256, 256, 0, stream>>>(dst, ew, deg, cnt, E);
  k_dinv   <<<(N+255)/256, 256, 0, stream>>>(deg, dinv, selfn, N);
  k_scan_a <<<NB, 256, 0, stream>>>(cnt, bsum, N);
  k_scan_b <<<1, 256, 0, stream>>>(bsum, boff, NB);
  k_scan_c <<<NB, 256, 0, stream>>>(cnt, boff, rowptr, next_, N, E);
  k_fill   <<<(E+255)/256, 256, 0, stream>>>(src, dst, ew, dinv, next_, csr_s, csr_n, E);
  k_find_starts<<<(N+255)/256, 256, 0, stream>>>(bat, start, N, G);
  k_packW  <<<64, 256, 0, stream>>>(W0, Bh0, Bl0);
  k_packW  <<<64, 256, 0, stream>>>(W1, Bh1, Bl1);
  k_packW  <<<64, 256, 0, stream>>>(W2, Bh2, Bl2);

  k_gemm_mfma<<<(N+63)/64, 256, 0, stream>>>(x, Bh0, Bl0, Y, N);
  k_gather<true><<<(N+3)/4, 256, 0, stream>>>((const unsigned int*)Y, rowptr, csr_s, csr_n,
                                              selfn, b0, g0, be0, m0, v0, H, N);
  k_gemm_mfma<<<(N+63)/64, 256, 0, stream>>>(H, Bh1, Bl1, Y, N);
  k_gather<true><<<(N+3)/4, 256, 0, stream>>>((const unsigned int*)Y, rowptr, csr_s, csr_n,
                                              selfn, b1, g1, be1, m1, v1, H, N);
  k_gemm_mfma<<<(N+63)/64, 256, 0, stream>>>(H, Bh2, Bl2, Y, N);
  k_gather<false><<<(N+3)/4, 256, 0, stream>>>((const unsigned int*)Y, rowptr, csr_s, csr_n,
                                               selfn, b2, nullptr, nullptr, nullptr, nullptr, H, N);
  k_pool<<<G, 1024, 0, stream>>>(H, start, out);
}

// Round 3
// 291.411 us; speedup vs baseline: 2.2817x; 1.3489x over previous
//
#include <hip/hip_runtime.h>

#define EPS 1e-5f
#define SLOPE 0.01f

typedef short short8 __attribute__((ext_vector_type(8)));
typedef float f32x4 __attribute__((ext_vector_type(4)));

static __device__ __forceinline__ unsigned short f32_to_bf16(float x){
  unsigned int u = __float_as_uint(x);
  unsigned int r = u + 0x7FFFu + ((u >> 16) & 1u);
  return (unsigned short)(r >> 16);
}
static __device__ __forceinline__ float bf16lo_to_f32(unsigned int v){
  return __uint_as_float(v << 16);
}
static __device__ __forceinline__ float bf16hi_to_f32(unsigned int v){
  return __uint_as_float(v & 0xFFFF0000u);
}

// ---- preprocessing -------------------------------------------------------

// one int atomic per edge; remember within-row position
__global__ void k_cnt(const int* __restrict__ dst, int* __restrict__ cnt,
                      int* __restrict__ pwr, int E){
  int e = blockIdx.x*blockDim.x + threadIdx.x;
  if (e >= E) return;
  pwr[e] = atomicAdd(&cnt[dst[e]], 1);
}

// 256-thread block exclusive scan helper
static __device__ __forceinline__ int blk_excl_scan(int v){
  __shared__ int wt[4];
  int lane = threadIdx.x & 63, wv = threadIdx.x >> 6;
  int incl = v;
  #pragma unroll
  for (int o = 1; o < 64; o <<= 1){
    int u = __shfl_up(incl, o, 64);
    if (lane >= o) incl += u;
  }
  if (lane == 63) wt[wv] = incl;
  __syncthreads();
  int off = 0;
  #pragma unroll
  for (int i = 0; i < 4; ++i) if (i < wv) off += wt[i];
  return off + incl - v;
}

__global__ void k_scan_a(const int* __restrict__ cnt, int* __restrict__ bsum, int n){
  int idx = blockIdx.x*256 + threadIdx.x;
  int v = (idx < n) ? cnt[idx] : 0;
  int ex = blk_excl_scan(v);
  if (threadIdx.x == 255) bsum[blockIdx.x] = ex + v;
}

__global__ void k_scan_b(const int* __restrict__ bsum, int* __restrict__ boff, int nb){
  int v = (threadIdx.x < nb) ? bsum[threadIdx.x] : 0;
  int ex = blk_excl_scan(v);
  if (threadIdx.x < nb) boff[threadIdx.x] = ex;
}

__global__ void k_scan_c(const int* __restrict__ cnt, const int* __restrict__ boff,
                         int* __restrict__ rowptr, int n, int Etot){
  int idx = blockIdx.x*256 + threadIdx.x;
  int v = (idx < n) ? cnt[idx] : 0;
  int ex = blk_excl_scan(v) + boff[blockIdx.x];
  if (idx < n) rowptr[idx] = ex;
  if (idx == 0) rowptr[n] = Etot;
}

// atomic-free fill: packed {src, w}
__global__ void k_fill(const int* __restrict__ src, const int* __restrict__ dst,
                       const float* __restrict__ w, const int* __restrict__ rowptr,
                       const int* __restrict__ pwr, int2* __restrict__ csr, int E){
  int e = blockIdx.x*blockDim.x + threadIdx.x;
  if (e >= E) return;
  int pos = rowptr[dst[e]] + pwr[e];
  csr[pos] = make_int2(src[e], __float_as_int(w[e]));
}

// deg from CSR row sums -> dinv, selfn
__global__ void k_deg_dinv(const int2* __restrict__ csr, const int* __restrict__ rowptr,
                           float* __restrict__ dinv, float* __restrict__ selfn, int n){
  int i = blockIdx.x*blockDim.x + threadIdx.x;
  if (i >= n) return;
  int a = rowptr[i], b = rowptr[i+1];
  float s = 1.0f;                       // self-loop weight
  for (int e = a; e < b; ++e) s += __int_as_float(csr[e].y);
  dinv[i]  = rsqrtf(s);
  selfn[i] = 1.0f / s;
}

// rewrite w -> dinv[src]*w*dinv[row]
__global__ void k_norm(int2* __restrict__ csr, const int* __restrict__ rowptr,
                       const float* __restrict__ dinv, int n){
  int i = blockIdx.x*blockDim.x + threadIdx.x;
  if (i >= n) return;
  int a = rowptr[i], b = rowptr[i+1];
  float dr = dinv[i];
  for (int e = a; e < b; ++e){
    int2 sn = csr[e];
    float nr = dinv[sn.x] * __int_as_float(sn.y) * dr;
    csr[e].y = __float_as_int(nr);
  }
}

__global__ void k_find_starts(const int* __restrict__ batch, int* __restrict__ start,
                              int n, int g){
  int i = blockIdx.x*blockDim.x + threadIdx.x;
  if (i >= n) return;
  int b  = batch[i];
  int bp = (i == 0) ? -1 : batch[i-1];
  for (int q = bp + 1; q <= b; ++q) start[q] = i;
  if (i == n - 1){
    for (int q = b + 1; q <= g; ++q) start[q] = n;
  }
}

// ---- weight pre-pack into MFMA B-fragment order (hi/lo bf16 split) -------
// B frag for tile t (n0=t*16), kstep s (k0=s*32), lane l, elem j:
//   value W[k][n], k = s*32 + (l>>4)*8 + j, n = t*16 + (l&15)

__global__ void k_packW3(const float* __restrict__ W0, const float* __restrict__ W1,
                         const float* __restrict__ W2, short* __restrict__ Bh,
                         short* __restrict__ Bl){
  int idx = blockIdx.x*256 + threadIdx.x;    // 0..49151
  int which = idx >> 14;
  int r = idx & 16383;
  const float* W = (which == 0) ? W0 : ((which == 1) ? W1 : W2);
  int j = r & 7;
  int l = (r >> 3) & 63;
  int s = (r >> 9) & 3;
  int t = r >> 11;
  int k = s*32 + ((l >> 4) << 3) + j;
  int n = t*16 + (l & 15);
  float v = W[k*128 + n];
  unsigned short hb = f32_to_bf16(v);
  float hf = bf16lo_to_f32(hb);
  unsigned short lb = f32_to_bf16(v - hf);
  Bh[idx] = (short)hb;
  Bl[idx] = (short)lb;
}

// ---- dense GEMM: Y[n,128](bf16) = X[n,128](f32) @ W (split-bf16 MFMA) ----

__global__ __launch_bounds__(256) void k_gemm_mfma(const float* __restrict__ X,
                                                   const short* __restrict__ Bh,
                                                   const short* __restrict__ Bl,
                                                   unsigned short* __restrict__ Y,
                                                   int nrows){
  int w    = threadIdx.x >> 6;
  int lane = threadIdx.x & 63;
  int m    = lane & 15;
  int kg   = lane >> 4;
  int row0 = blockIdx.x*64 + w*16;

  f32x4 acc[8];
  #pragma unroll
  for (int t = 0; t < 8; ++t) acc[t] = (f32x4){0.f, 0.f, 0.f, 0.f};

  int arow = row0 + m;
  if (arow >= nrows) arow = nrows - 1;
  const float* ap0 = X + (size_t)arow*128 + (kg << 3);

  const short8* bh0 = (const short8*)Bh + lane;
  const short8* bl0 = (const short8*)Bl + lane;

  #pragma unroll
  for (int s = 0; s < 4; ++s){
    const float* ap = ap0 + s*32;
    float4 a0 = *(const float4*)ap;
    float4 a1 = *(const float4*)(ap + 4);
    float av[8] = {a0.x, a0.y, a0.z, a0.w, a1.x, a1.y, a1.z, a1.w};
    short8 ah, al;
    #pragma unroll
    for (int j = 0; j < 8; ++j){
      unsigned short hb = f32_to_bf16(av[j]);
      float hf = bf16lo_to_f32(hb);
      ah[j] = (short)hb;
      al[j] = (short)f32_to_bf16(av[j] - hf);
    }
    #pragma unroll
    for (int t = 0; t < 8; ++t){
      short8 bh = bh0[t*256 + s*64];
      short8 bl = bl0[t*256 + s*64];
      acc[t] = __builtin_amdgcn_mfma_f32_16x16x32_bf16(ah, bh, acc[t], 0, 0, 0);
      acc[t] = __builtin_amdgcn_mfma_f32_16x16x32_bf16(al, bh, acc[t], 0, 0, 0);
      acc[t] = __builtin_amdgcn_mfma_f32_16x16x32_bf16(ah, bl, acc[t], 0, 0, 0);
    }
  }

  // C/D: col = lane&15, row = (lane>>4)*4 + reg
  #pragma unroll
  for (int t = 0; t < 8; ++t){
    #pragma unroll
    for (int r = 0; r < 4; ++r){
      int grow = row0 + (kg << 2) + r;
      if (grow < nrows) Y[(size_t)grow*128 + t*16 + m] = f32_to_bf16(acc[t][r]);
    }
  }
}

// ---- CSR gather + bias (+BN+leaky); Y bf16, out f32 ----------------------
// one wave per node; 16 lanes per edge slot, 4 slots; lane loads 16B (8 ch)

template<bool BN>
__global__ __launch_bounds__(256) void k_gather(
    const unsigned short* __restrict__ Y, const int* __restrict__ rowptr,
    const int2* __restrict__ csr, const float* __restrict__ selfn,
    const float* __restrict__ bias,
    const float* __restrict__ gam, const float* __restrict__ bet,
    const float* __restrict__ mean, const float* __restrict__ var,
    float* __restrict__ out, int n){
  int wid  = (blockIdx.x * blockDim.x + threadIdx.x) >> 6;   // node
  int lane = threadIdx.x & 63;
  if (wid >= n) return;
  int g = lane >> 4;          // edge slot 0..3
  int q = lane & 15;          // channel quad (8 channels)

  float acc[8];
  #pragma unroll
  for (int j = 0; j < 8; ++j) acc[j] = 0.f;

  int e0 = rowptr[wid], e1 = rowptr[wid+1];
  const char* Yb = (const char*)Y;

  int e = e0 + g;
  for (; e + 4 < e1; e += 8){
    int2 sn0 = csr[e];
    int2 sn1 = csr[e+4];
    float n0 = __int_as_float(sn0.y);
    float n1 = __int_as_float(sn1.y);
    uint4 v0 = *(const uint4*)(Yb + ((size_t)sn0.x << 8) + (q << 4));
    uint4 v1 = *(const uint4*)(Yb + ((size_t)sn1.x << 8) + (q << 4));
    acc[0] += bf16lo_to_f32(v0.x)*n0; acc[1] += bf16hi_to_f32(v0.x)*n0;
    acc[2] += bf16lo_to_f32(v0.y)*n0; acc[3] += bf16hi_to_f32(v0.y)*n0;
    acc[4] += bf16lo_to_f32(v0.z)*n0; acc[5] += bf16hi_to_f32(v0.z)*n0;
    acc[6] += bf16lo_to_f32(v0.w)*n0; acc[7] += bf16hi_to_f32(v0.w)*n0;
    acc[0] += bf16lo_to_f32(v1.x)*n1; acc[1] += bf16hi_to_f32(v1.x)*n1;
    acc[2] += bf16lo_to_f32(v1.y)*n1; acc[3] += bf16hi_to_f32(v1.y)*n1;
    acc[4] += bf16lo_to_f32(v1.z)*n1; acc[5] += bf16hi_to_f32(v1.z)*n1;
    acc[6] += bf16lo_to_f32(v1.w)*n1; acc[7] += bf16hi_to_f32(v1.w)*n1;
  }
  if (e < e1){
    int2 sn0 = csr[e];
    float n0 = __int_as_float(sn0.y);
    uint4 v0 = *(const uint4*)(Yb + ((size_t)sn0.x << 8) + (q << 4));
    acc[0] += bf16lo_to_f32(v0.x)*n0; acc[1] += bf16hi_to_f32(v0.x)*n0;
    acc[2] += bf16lo_to_f32(v0.y)*n0; acc[3] += bf16hi_to_f32(v0.y)*n0;
    acc[4] += bf16lo_to_f32(v0.z)*n0; acc[5] += bf16hi_to_f32(v0.z)*n0;
    acc[6] += bf16lo_to_f32(v0.w)*n0; acc[7] += bf16hi_to_f32(v0.w)*n0;
  }

  // combine the 4 edge slots
  #pragma unroll
  for (int j = 0; j < 8; ++j){
    acc[j] += __shfl_xor(acc[j], 16, 64);
    acc[j] += __shfl_xor(acc[j], 32, 64);
  }

  if (g == 0){
    // self term
    uint4 v = *(const uint4*)(Yb + ((size_t)wid << 8) + (q << 4));
    float sf = selfn[wid];
    acc[0] += bf16lo_to_f32(v.x)*sf; acc[1] += bf16hi_to_f32(v.x)*sf;
    acc[2] += bf16lo_to_f32(v.y)*sf; acc[3] += bf16hi_to_f32(v.y)*sf;
    acc[4] += bf16lo_to_f32(v.z)*sf; acc[5] += bf16hi_to_f32(v.z)*sf;
    acc[6] += bf16lo_to_f32(v.w)*sf; acc[7] += bf16hi_to_f32(v.w)*sf;

    int c = q << 3;
    float4 bi0 = *(const float4*)&bias[c];
    float4 bi1 = *(const float4*)&bias[c+4];
    float o[8] = {acc[0]+bi0.x, acc[1]+bi0.y, acc[2]+bi0.z, acc[3]+bi0.w,
                  acc[4]+bi1.x, acc[5]+bi1.y, acc[6]+bi1.z, acc[7]+bi1.w};
    if (BN){
      float4 ga0 = *(const float4*)&gam[c],  ga1 = *(const float4*)&gam[c+4];
      float4 bt0 = *(const float4*)&bet[c],  bt1 = *(const float4*)&bet[c+4];
      float4 mn0 = *(const float4*)&mean[c], mn1 = *(const float4*)&mean[c+4];
      float4 vr0 = *(const float4*)&var[c],  vr1 = *(const float4*)&var[c+4];
      float gv[8] = {ga0.x,ga0.y,ga0.z,ga0.w, ga1.x,ga1.y,ga1.z,ga1.w};
      float bv[8] = {bt0.x,bt0.y,bt0.z,bt0.w, bt1.x,bt1.y,bt1.z,bt1.w};
      float mv[8] = {mn0.x,mn0.y,mn0.z,mn0.w, mn1.x,mn1.y,mn1.z,mn1.w};
      float vv[8] = {vr0.x,vr0.y,vr0.z,vr0.w, vr1.x,vr1.y,vr1.z,vr1.w};
      #pragma unroll
      for (int j = 0; j < 8; ++j){
        float a = gv[j] * rsqrtf(vv[j] + EPS);
        float t = (o[j] - mv[j]) * a + bv[j];
        o[j] = t > 0.f ? t : SLOPE*t;
      }
    }
    float4* op = (float4*)(out + (size_t)wid*128 + c);
    op[0] = make_float4(o[0], o[1], o[2], o[3]);
    op[1] = make_float4(o[4], o[5], o[6], o[7]);
  }
}

// ---- mean pool over sorted batch ----------------------------------------

__global__ void k_pool(const float* __restrict__ h, const int* __restrict__ start,
                       float* __restrict__ out){
  __shared__ float red[1024];
  int g = blockIdx.x;
  int a = start[g], b = start[g+1];
  int rg = threadIdx.x >> 7;     // 0..7
  int c  = threadIdx.x & 127;
  float s = 0.f;
  for (int i = a + rg; i < b; i += 8) s += h[(size_t)i*128 + c];
  red[threadIdx.x] = s;
  __syncthreads();
  if (rg == 0){
    float tot = 0.f;
    #pragma unroll
    for (int q = 0; q < 8; ++q) tot += red[c + q*128];
    int cn = b - a;
    out[g*128 + c] = tot / (float)(cn > 0 ? cn : 1);
  }
}

// ---- launch --------------------------------------------------------------

extern "C" void kernel_launch(void* const* d_in, const int* in_sizes, int n_in,
                              void* d_out, int out_size, void* d_ws, size_t ws_size,
                              hipStream_t stream) {
  const int N = in_sizes[0] / 128;
  const int E = in_sizes[1];
  const int G = out_size / 128;
  const int NB = (N + 255) / 256;        // scan blocks

  const float* x   = (const float*)d_in[0];
  const float* ew  = (const float*)d_in[1];
  const float* W0  = (const float*)d_in[2];
  const float* b0  = (const float*)d_in[3];
  const float* W1  = (const float*)d_in[4];
  const float* b1  = (const float*)d_in[5];
  const float* W2  = (const float*)d_in[6];
  const float* b2  = (const float*)d_in[7];
  const float* g0  = (const float*)d_in[8];
  const float* be0 = (const float*)d_in[9];
  const float* m0  = (const float*)d_in[10];
  const float* v0  = (const float*)d_in[11];
  const float* g1  = (const float*)d_in[12];
  const float* be1 = (const float*)d_in[13];
  const float* m1  = (const float*)d_in[14];
  const float* v1  = (const float*)d_in[15];
  const int*   ei  = (const int*)d_in[16];
  const int*   bat = (const int*)d_in[17];
  float* out = (float*)d_out;

  char* p = (char*)d_ws;
  auto alloc = [&](size_t bytes)->char*{
    char* q = p; p += (bytes + 255) & ~(size_t)255; return q;
  };
  float* dinv   = (float*)alloc((size_t)N*4);
  float* selfn  = (float*)alloc((size_t)N*4);
  int*   cnt    = (int*)  alloc((size_t)N*4);
  int*   rowptr = (int*)  alloc((size_t)(N+1)*4);
  int*   pwr    = (int*)  alloc((size_t)E*4);
  int*   start  = (int*)  alloc((size_t)(G+1)*4);
  int*   bsum   = (int*)  alloc((size_t)NB*4);
  int*   boff   = (int*)  alloc((size_t)NB*4);
  int2*  csr    = (int2*) alloc((size_t)E*8);
  unsigned short* Y = (unsigned short*)alloc((size_t)N*128*2);
  float* H      = (float*)alloc((size_t)N*128*4);
  short* Bh = (short*)alloc(3*16384*2);
  short* Bl = (short*)alloc(3*16384*2);

  hipMemsetAsync(cnt, 0, (size_t)N*4, stream);

  const int* src = ei;
  const int* dst = ei + E;

  k_cnt    <<<(E+255)/256, 256, 0, stream>>>(dst, cnt, pwr, E);
  k_scan_a <<<NB, 256, 0, stream>>>(cnt, bsum, N);
  k_scan_b <<<1, 256, 0, stream>>>(bsum, boff, NB);
  k_scan_c <<<NB, 256, 0, stream>>>(cnt, boff, rowptr, N, E);
  k_fill   <<<(E+255)/256, 256, 0, stream>>>(src, dst, ew, rowptr, pwr, csr, E);
  k_deg_dinv<<<(N+255)/256, 256, 0, stream>>>(csr, rowptr, dinv, selfn, N);
  k_norm   <<<(N+255)/256, 256, 0, stream>>>(csr, rowptr, dinv, N);
  k_find_starts<<<(N+255)/256, 256, 0, stream>>>(bat, start, N, G);
  k_packW3 <<<192, 256, 0, stream>>>(W0, W1, W2, Bh, Bl);

  k_gemm_mfma<<<(N+63)/64, 256, 0, stream>>>(x, Bh, Bl, Y, N);
  k_gather<true><<<(N+3)/4, 256, 0, stream>>>(Y, rowptr, csr, selfn,
                                              b0, g0, be0, m0, v0, H, N);
  k_gemm_mfma<<<(N+63)/64, 256, 0, stream>>>(H, Bh + 16384, Bl + 16384, Y, N);
  k_gather<true><<<(N+3)/4, 256, 0, stream>>>(Y, rowptr, csr, selfn,
                                              b1, g1, be1, m1, v1, H, N);
  k_gemm_mfma<<<(N+63)/64, 256, 0, stream>>>(H, Bh + 32768, Bl + 32768, Y, N);
  k_gather<false><<<(N+3)/4, 256, 0, stream>>>(Y, rowptr, csr, selfn,
                                               b2, nullptr, nullptr, nullptr, nullptr, H, N);
  k_pool<<<G, 1024, 0, stream>>>(H, start, out);
}